// Round 1
// baseline (1223.348 us; speedup 1.0000x reference)
//
#include <hip/hip_runtime.h>
#include <hip/hip_bf16.h>
#include <math.h>

typedef __attribute__((ext_vector_type(8))) short bf16x8;
typedef __attribute__((ext_vector_type(4))) float f32x4;
typedef __hip_bfloat16 bf16;

#define NH 12
#define HD 32
#define NPAD 64
#define NWIN 2048
#define NTOK 100352
#define HBLK (NPAD*HD)        // 2048 elements per (head) block
#define WBLK (3*NH*HBLK)      // 73728 elements per window

__device__ inline float wave_sum(float v) {
#pragma unroll
  for (int off = 32; off; off >>= 1) v += __shfl_xor(v, off);
  return v;
}

// ---------------- weight cast + transpose: in (K x N) f32 -> out (N x K) bf16
__global__ __launch_bounds__(256) void cast_transpose(const float* __restrict__ in,
                                                      bf16* __restrict__ out, int K, int N) {
  int e = blockIdx.x * 256 + threadIdx.x;
  if (e >= K * N) return;
  int n = e / K, k = e - n * K;
  out[e] = __float2bfloat16(in[k * N + n]);
}

// ---------------- zero the 15 pad rows of every (w, which, h) QKV block
__global__ __launch_bounds__(256) void zero_pads(bf16* __restrict__ qkv) {
  int idx = blockIdx.x * 256 + threadIdx.x;
  const int total = NWIN * 3 * NH * 15 * HD;
  if (idx >= total) return;
  int d = idx & 31; int rest = idx >> 5;
  int n = 49 + (rest % 15); rest /= 15;
  int h = rest % NH; rest /= NH;
  int which = rest % 3; int w = rest / 3;
  size_t base = (size_t)w * WBLK + (size_t)which * NH * HBLK + (size_t)h * HBLK;
  size_t addr = (which == 2) ? base + (size_t)d * NPAD + n : base + (size_t)n * HD + d;
  qkv[addr] = __float2bfloat16(0.0f);
}

// ---------------- LayerNorm. MODE 0: LN1 + roll(-3,-3) + window partition (src mapped)
//                  MODE 1: LN2 straight rows
template <int MODE>
__global__ __launch_bounds__(256) void ln_kernel(const float* __restrict__ x,
                                                 const float* __restrict__ g,
                                                 const float* __restrict__ be,
                                                 bf16* __restrict__ out) {
  int wv = threadIdx.x >> 6, lane = threadIdx.x & 63;
  int t = blockIdx.x * 4 + wv;
  size_t src;
  if (MODE == 0) {
    int w = t / 49, n = t - w * 49;
    int b = w >> 6, wi = w & 63;
    int wy = wi >> 3, wx = wi & 7;
    int py = n / 7, px = n - py * 7;
    int rr = wy * 7 + py, cc = wx * 7 + px;
    int ro = rr + 3; if (ro >= 56) ro -= 56;
    int co = cc + 3; if (co >= 56) co -= 56;
    src = (size_t)b * 3136 + ro * 56 + co;
  } else {
    src = (size_t)t;
  }
  const float* row = x + src * 384;
  float v[6]; float s = 0.f;
#pragma unroll
  for (int j = 0; j < 6; ++j) { v[j] = row[lane + 64 * j]; s += v[j]; }
  s = wave_sum(s);
  float mu = s * (1.f / 384.f);
  float q = 0.f;
#pragma unroll
  for (int j = 0; j < 6; ++j) { float d = v[j] - mu; q += d * d; }
  q = wave_sum(q);
  float rs = rsqrtf(q * (1.f / 384.f) + 1e-5f);
  bf16* o = out + (size_t)t * 384;
#pragma unroll
  for (int j = 0; j < 6; ++j) {
    int c = lane + 64 * j;
    o[c] = __float2bfloat16((v[j] - mu) * rs * g[c] + be[c]);
  }
}

// ---------------- GEMM: C = A(M x K) * B(K x N), B given transposed (N x K), bf16 in fp32 acc.
// 128x128 tile, BK=32, 4 waves each 64x64. EPI: 0=QKV scatter, 1=proj+residual+reverse,
// 2=GELU->h1, 3=out=acc+b2+x1 -> d_out
#define LDA 40
template <int EPI>
__global__ __launch_bounds__(256) void gemm_bf16(const bf16* __restrict__ A,
                                                 const bf16* __restrict__ BT,
                                                 int K, int row0,
                                                 const float* __restrict__ bias,
                                                 const float* __restrict__ extra,
                                                 void* __restrict__ outp) {
  __shared__ __align__(16) bf16 As[128 * LDA];
  __shared__ __align__(16) bf16 Bs[128 * LDA];
  int tid = threadIdx.x;
  int lane = tid & 63, wv = tid >> 6;
  int wr = wv >> 1, wc = wv & 1;
  int lr = lane & 15, lg = lane >> 4;
  int brow = blockIdx.y, bcol = blockIdx.x;
  const bf16* Ab = A + (size_t)brow * 128 * K;
  const bf16* Bb = BT + (size_t)bcol * 128 * K;

  f32x4 acc[4][4] = {};
  int r0 = tid >> 2;
  int c8 = (tid & 3) * 8;
  int nk = K >> 5;
  for (int kk = 0; kk < nk; ++kk) {
    int k0 = kk << 5;
#pragma unroll
    for (int i = 0; i < 2; ++i) {
      int rowi = r0 + i * 64;
      *(int4*)(&As[rowi * LDA + c8]) = *(const int4*)(Ab + (size_t)rowi * K + k0 + c8);
      *(int4*)(&Bs[rowi * LDA + c8]) = *(const int4*)(Bb + (size_t)rowi * K + k0 + c8);
    }
    __syncthreads();
    bf16x8 a[4], b[4];
#pragma unroll
    for (int t4 = 0; t4 < 4; ++t4) {
      a[t4] = *(const bf16x8*)(&As[(wr * 64 + t4 * 16 + lr) * LDA + lg * 8]);
      b[t4] = *(const bf16x8*)(&Bs[(wc * 64 + t4 * 16 + lr) * LDA + lg * 8]);
    }
#pragma unroll
    for (int i = 0; i < 4; ++i)
#pragma unroll
      for (int j = 0; j < 4; ++j)
        acc[i][j] = __builtin_amdgcn_mfma_f32_16x16x32_bf16(a[i], b[j], acc[i][j], 0, 0, 0);
    __syncthreads();
  }

  // epilogue
  float bs[4];
#pragma unroll
  for (int j = 0; j < 4; ++j) bs[j] = bias[bcol * 128 + wc * 64 + j * 16 + lr];

#pragma unroll
  for (int i = 0; i < 4; ++i) {
#pragma unroll
    for (int r = 0; r < 4; ++r) {
      int lrow = brow * 128 + wr * 64 + i * 16 + lg * 4 + r;  // chunk-local row
      int grow = row0 + lrow;                                  // global row
      // row-dependent precompute
      int w_ = 0, n_ = 0; size_t tok = 0;
      if (EPI == 0 || EPI == 1) {
        w_ = grow / 49; n_ = grow - w_ * 49;
        if (EPI == 1) {
          int b_ = w_ >> 6, wi = w_ & 63;
          int wy = wi >> 3, wx = wi & 7;
          int py = n_ / 7, px = n_ - py * 7;
          int rr = wy * 7 + py, cc = wx * 7 + px;
          int ro = rr + 3; if (ro >= 56) ro -= 56;
          int co = cc + 3; if (co >= 56) co -= 56;
          tok = (size_t)b_ * 3136 + ro * 56 + co;
        }
      }
#pragma unroll
      for (int j = 0; j < 4; ++j) {
        int col = bcol * 128 + wc * 64 + j * 16 + lr;
        float val = acc[i][j][r] + bs[j];
        if (EPI == 0) {
          int which = (col >= 768) ? 2 : (col >= 384 ? 1 : 0);
          int cc = col - which * 384;
          int h = cc >> 5, d = cc & 31;
          size_t base = (size_t)w_ * WBLK + (size_t)which * NH * HBLK + (size_t)h * HBLK;
          size_t addr = (which == 2) ? base + (size_t)d * NPAD + n_ : base + (size_t)n_ * HD + d;
          ((bf16*)outp)[addr] = __float2bfloat16(val);
        } else if (EPI == 1) {
          size_t idx = tok * 384 + col;
          ((float*)outp)[idx] = val + extra[idx];
        } else if (EPI == 2) {
          float gv = 0.5f * val * (1.0f + erff(val * 0.70710678118654752f));
          ((bf16*)outp)[(size_t)lrow * 1536 + col] = __float2bfloat16(gv);
        } else {
          size_t idx = (size_t)grow * 384 + col;
          ((float*)outp)[idx] = val + extra[idx];
        }
      }
    }
  }
}

// ---------------- windowed attention: 1 block per window, 4 waves x 3 heads
__global__ __launch_bounds__(256) void attn_kernel(const bf16* __restrict__ qkv,
                                                   const float* __restrict__ rel,
                                                   bf16* __restrict__ attn_out) {
  __shared__ __align__(16) bf16 P[4][64 * 72];
  int wv = threadIdx.x >> 6, lane = threadIdx.x & 63;
  int lr = lane & 15, lg = lane >> 4;
  int w = blockIdx.x;
  int wi = w & 63, wy = wi >> 3, wx = wi & 7;
  const bf16* base = qkv + (size_t)w * WBLK;
  bf16* Pl = &P[wv][0];
  const float scale = 0.17677669529663689f;

  for (int hh = 0; hh < 3; ++hh) {
    int h = wv + hh * 4;
    const bf16* Q  = base + (size_t)h * HBLK;
    const bf16* Kp = base + (size_t)(NH + h) * HBLK;
    const bf16* Vt = base + (size_t)(2 * NH + h) * HBLK;

    bf16x8 qa[4], kb[4];
#pragma unroll
    for (int t = 0; t < 4; ++t) {
      qa[t] = *(const bf16x8*)(Q  + (t * 16 + lr) * 32 + lg * 8);
      kb[t] = *(const bf16x8*)(Kp + (t * 16 + lr) * 32 + lg * 8);
    }
    f32x4 S[4][4] = {};
#pragma unroll
    for (int i = 0; i < 4; ++i)
#pragma unroll
      for (int j = 0; j < 4; ++j)
        S[i][j] = __builtin_amdgcn_mfma_f32_16x16x32_bf16(qa[i], kb[j], S[i][j], 0, 0, 0);

    // bias + mask + softmax, row = i*16 + lg*4 + r (query), col = j*16 + lr (key)
#pragma unroll
    for (int i = 0; i < 4; ++i) {
#pragma unroll
      for (int r = 0; r < 4; ++r) {
        int row = i * 16 + lg * 4 + r;
        bool rowok = row < 49;
        int py = row / 7, px = row - py * 7;
        int regi = 0;
        if (rowok) {
          int ry = wy * 7 + py, rx = wx * 7 + px;
          int ly = ry < 49 ? 0 : (ry < 53 ? 1 : 2);
          int lx = rx < 49 ? 0 : (rx < 53 ? 1 : 2);
          regi = ly * 3 + lx;
        }
        float sv[4]; float m = -1e30f;
#pragma unroll
        for (int j = 0; j < 4; ++j) {
          int col = j * 16 + lr;
          float s = -1e30f;
          if (rowok && col < 49) {
            int qy = col / 7, qx = col - qy * 7;
            int cy = wy * 7 + qy, cx = wx * 7 + qx;
            int lyc = cy < 49 ? 0 : (cy < 53 ? 1 : 2);
            int lxc = cx < 49 ? 0 : (cx < 53 ? 1 : 2);
            int regj = lyc * 3 + lxc;
            int ridx = (py - qy + 6) * 13 + (px - qx + 6);
            s = S[i][j][r] * scale + rel[ridx * 12 + h] + (regi == regj ? 0.f : -100.f);
          }
          sv[j] = s;
          m = fmaxf(m, s);
        }
        m = fmaxf(m, __shfl_xor(m, 1));
        m = fmaxf(m, __shfl_xor(m, 2));
        m = fmaxf(m, __shfl_xor(m, 4));
        m = fmaxf(m, __shfl_xor(m, 8));
        float ev[4]; float sum = 0.f;
#pragma unroll
        for (int j = 0; j < 4; ++j) { ev[j] = __expf(sv[j] - m); sum += ev[j]; }
        sum += __shfl_xor(sum, 1);
        sum += __shfl_xor(sum, 2);
        sum += __shfl_xor(sum, 4);
        sum += __shfl_xor(sum, 8);
        float inv = 1.0f / sum;
#pragma unroll
        for (int j = 0; j < 4; ++j)
          Pl[row * 72 + j * 16 + lr] = __float2bfloat16(ev[j] * inv);
      }
    }

    // PV: O(64x32) = P(64x64) * V(64x32); V from transposed layout Vt (32 x 64)
    bf16x8 vb[2][2];
#pragma unroll
    for (int kt = 0; kt < 2; ++kt)
#pragma unroll
      for (int cj = 0; cj < 2; ++cj)
        vb[kt][cj] = *(const bf16x8*)(Vt + (cj * 16 + lr) * 64 + kt * 32 + lg * 8);
    f32x4 O[4][2] = {};
#pragma unroll
    for (int i = 0; i < 4; ++i) {
#pragma unroll
      for (int kt = 0; kt < 2; ++kt) {
        bf16x8 pa = *(const bf16x8*)(Pl + (i * 16 + lr) * 72 + kt * 32 + lg * 8);
#pragma unroll
        for (int cj = 0; cj < 2; ++cj)
          O[i][cj] = __builtin_amdgcn_mfma_f32_16x16x32_bf16(pa, vb[kt][cj], O[i][cj], 0, 0, 0);
      }
    }
#pragma unroll
    for (int i = 0; i < 4; ++i)
#pragma unroll
      for (int cj = 0; cj < 2; ++cj)
#pragma unroll
        for (int r = 0; r < 4; ++r) {
          int n = i * 16 + lg * 4 + r;
          if (n < 49)
            attn_out[((size_t)w * 49 + n) * 384 + h * 32 + cj * 16 + lr] =
                __float2bfloat16(O[i][cj][r]);
        }
  }
}

extern "C" void kernel_launch(void* const* d_in, const int* in_sizes, int n_in,
                              void* d_out, int out_size, void* d_ws, size_t ws_size,
                              hipStream_t stream) {
  (void)in_sizes; (void)n_in; (void)out_size;
  const float* x     = (const float*)d_in[0];
  const float* g1    = (const float*)d_in[1];
  const float* be1   = (const float*)d_in[2];
  const float* w_qkv = (const float*)d_in[3];
  const float* b_qkv = (const float*)d_in[4];
  const float* rel   = (const float*)d_in[5];
  const float* w_pr  = (const float*)d_in[6];
  const float* b_pr  = (const float*)d_in[7];
  const float* g2    = (const float*)d_in[8];
  const float* be2   = (const float*)d_in[9];
  const float* w1    = (const float*)d_in[10];
  const float* b1    = (const float*)d_in[11];
  const float* w2    = (const float*)d_in[12];
  const float* b2    = (const float*)d_in[13];
  float* out = (float*)d_out;

  if (ws_size < 390070272u) return;  // layout below needs ~372 MiB

  char* ws = (char*)d_ws;
  bf16* wqkvT = (bf16*)(ws);                     // 1152 x 384
  bf16* wprT  = (bf16*)(ws + 884736);            // 384 x 384
  bf16* w1T   = (bf16*)(ws + 1179648);           // 1536 x 384
  bf16* w2T   = (bf16*)(ws + 2359296);           // 384 x 1536
  bf16* xw    = (bf16*)(ws + (4u << 20));        // 100352 x 384 bf16 (also attn_out)
  bf16* qkv   = (bf16*)(ws + (84u << 20));       // 2048 * 73728 bf16 padded QKV
  bf16* m_in  = qkv;                             // reuse after attention
  bf16* h1    = (bf16*)(ws + (164u << 20));      // 50176 x 1536 bf16 chunk

  cast_transpose<<<dim3((442368 + 255) / 256), 256, 0, stream>>>(w_qkv, wqkvT, 384, 1152);
  cast_transpose<<<dim3((147456 + 255) / 256), 256, 0, stream>>>(w_pr, wprT, 384, 384);
  cast_transpose<<<dim3((589824 + 255) / 256), 256, 0, stream>>>(w1, w1T, 384, 1536);
  cast_transpose<<<dim3((589824 + 255) / 256), 256, 0, stream>>>(w2, w2T, 1536, 384);

  zero_pads<<<dim3((NWIN * 3 * NH * 15 * HD + 255) / 256), 256, 0, stream>>>(qkv);

  ln_kernel<0><<<dim3(NTOK / 4), 256, 0, stream>>>(x, g1, be1, xw);

  gemm_bf16<0><<<dim3(9, 784), 256, 0, stream>>>(xw, wqkvT, 384, 0, b_qkv, nullptr, (void*)qkv);

  attn_kernel<<<dim3(NWIN), 256, 0, stream>>>(qkv, rel, xw);

  gemm_bf16<1><<<dim3(3, 784), 256, 0, stream>>>(xw, wprT, 384, 0, b_pr, x, (void*)out);

  ln_kernel<1><<<dim3(NTOK / 4), 256, 0, stream>>>(out, g2, be2, m_in);

  for (int c = 0; c < 2; ++c) {
    gemm_bf16<2><<<dim3(12, 392), 256, 0, stream>>>(m_in + (size_t)c * 50176 * 384, w1T, 384,
                                                    c * 50176, b1, nullptr, (void*)h1);
    gemm_bf16<3><<<dim3(3, 392), 256, 0, stream>>>(h1, w2T, 1536, c * 50176, b2, out,
                                                   (void*)out);
  }
}

// Round 2
// 1189.902 us; speedup vs baseline: 1.0281x; 1.0281x over previous
//
#include <hip/hip_runtime.h>
#include <hip/hip_bf16.h>
#include <math.h>

typedef __attribute__((ext_vector_type(8))) short bf16x8;
typedef __attribute__((ext_vector_type(4))) float f32x4;
typedef __hip_bfloat16 bf16;

#define NH 12
#define HD 32
#define NPAD 64
#define NWIN 2048
#define NTOK 100352
#define HBLK (NPAD*HD)        // 2048 elements per (head) block
#define WBLK (3*NH*HBLK)      // 73728 elements per window

__device__ inline float wave_sum(float v) {
#pragma unroll
  for (int off = 32; off; off >>= 1) v += __shfl_xor(v, off);
  return v;
}

__device__ inline void load_lds16(const bf16* g, bf16* l) {
  __builtin_amdgcn_global_load_lds((const __attribute__((address_space(1))) void*)g,
                                   (__attribute__((address_space(3))) void*)l, 16, 0, 0);
}

// ---------------- weight cast + transpose: in (K x N) f32 -> out (N x K) bf16
__global__ __launch_bounds__(256) void cast_transpose(const float* __restrict__ in,
                                                      bf16* __restrict__ out, int K, int N) {
  int e = blockIdx.x * 256 + threadIdx.x;
  if (e >= K * N) return;
  int n = e / K, k = e - n * K;
  out[e] = __float2bfloat16(in[k * N + n]);
}

// ---------------- zero the 15 pad rows of every (w, which, h) QKV block
__global__ __launch_bounds__(256) void zero_pads(bf16* __restrict__ qkv) {
  int idx = blockIdx.x * 256 + threadIdx.x;
  const int total = NWIN * 3 * NH * 15 * HD;
  if (idx >= total) return;
  int d = idx & 31; int rest = idx >> 5;
  int n = 49 + (rest % 15); rest /= 15;
  int h = rest % NH; rest /= NH;
  int which = rest % 3; int w = rest / 3;
  size_t base = (size_t)w * WBLK + (size_t)which * NH * HBLK + (size_t)h * HBLK;
  size_t addr = (which == 2) ? base + (size_t)d * NPAD + n : base + (size_t)n * HD + d;
  qkv[addr] = __float2bfloat16(0.0f);
}

// ---------------- LayerNorm. MODE 0: LN1 + roll(-3,-3) + window partition (src mapped)
//                  MODE 1: LN2 straight rows
template <int MODE>
__global__ __launch_bounds__(256) void ln_kernel(const float* __restrict__ x,
                                                 const float* __restrict__ g,
                                                 const float* __restrict__ be,
                                                 bf16* __restrict__ out) {
  int wv = threadIdx.x >> 6, lane = threadIdx.x & 63;
  int t = blockIdx.x * 4 + wv;
  size_t src;
  if (MODE == 0) {
    int w = t / 49, n = t - w * 49;
    int b = w >> 6, wi = w & 63;
    int wy = wi >> 3, wx = wi & 7;
    int py = n / 7, px = n - py * 7;
    int rr = wy * 7 + py, cc = wx * 7 + px;
    int ro = rr + 3; if (ro >= 56) ro -= 56;
    int co = cc + 3; if (co >= 56) co -= 56;
    src = (size_t)b * 3136 + ro * 56 + co;
  } else {
    src = (size_t)t;
  }
  const float* row = x + src * 384;
  float v[6]; float s = 0.f;
#pragma unroll
  for (int j = 0; j < 6; ++j) { v[j] = row[lane + 64 * j]; s += v[j]; }
  s = wave_sum(s);
  float mu = s * (1.f / 384.f);
  float q = 0.f;
#pragma unroll
  for (int j = 0; j < 6; ++j) { float d = v[j] - mu; q += d * d; }
  q = wave_sum(q);
  float rs = rsqrtf(q * (1.f / 384.f) + 1e-5f);
  bf16* o = out + (size_t)t * 384;
#pragma unroll
  for (int j = 0; j < 6; ++j) {
    int c = lane + 64 * j;
    o[c] = __float2bfloat16((v[j] - mu) * rs * g[c] + be[c]);
  }
}

// ---------------- GEMM (m97 structure): C = A(M x K) * B^T, 128x128 tile, BK=32,
// global_load_lds width-16 staging, linear [128][32] LDS, XCD-swizzled 1-D grid.
// EPI: 0=QKV scatter, 1=proj+residual+reverse, 2=GELU->h1, 3=out=acc+b2+x1 -> d_out
template <int EPI>
__global__ __launch_bounds__(256) void gemm_bf16(const bf16* __restrict__ A,
                                                 const bf16* __restrict__ BT,
                                                 int K, int NCOL, int row0,
                                                 const float* __restrict__ bias,
                                                 const float* __restrict__ extra,
                                                 void* __restrict__ outp) {
  __shared__ __align__(16) bf16 As[128 * 32];
  __shared__ __align__(16) bf16 Bs[128 * 32];
  int tid = threadIdx.x;
  int lane = tid & 63, wv = tid >> 6;
  int wr = wv >> 1, wc = wv & 1;
  int lr = lane & 15, lg = lane >> 4;

  // XCD-aware swizzle: nwg % 8 == 0 and (nwg/8) % NCOL == 0 guaranteed by launch.
  int nwg = gridDim.x;
  int dd = blockIdx.x;
  int xcd = dd & 7, idx = dd >> 3;
  int perx = nwg >> 3;
  int q = idx / NCOL;
  int brow = xcd * (perx / NCOL) + q;
  int bcol = idx - q * NCOL;

  const bf16* Ab = A + (size_t)brow * 128 * K;
  const bf16* Bb = BT + (size_t)bcol * 128 * K;

  // staging map: chunk c = wv*2 + i covers LDS bytes [c*1024, c*1024+1024)
  // lane offset = lane*16B -> elem = c*512 + lane*8 -> row = c*16 + lane/4, col = (lane&3)*8
  int c0 = wv * 2, c1 = c0 + 1;
  int rsub = lane >> 2;
  int csub = (lane & 3) * 8;
  const bf16* ap0 = Ab + (size_t)(c0 * 16 + rsub) * K + csub;
  const bf16* ap1 = Ab + (size_t)(c1 * 16 + rsub) * K + csub;
  const bf16* bp0 = Bb + (size_t)(c0 * 16 + rsub) * K + csub;
  const bf16* bp1 = Bb + (size_t)(c1 * 16 + rsub) * K + csub;
  bf16* lA0 = &As[c0 * 512]; bf16* lA1 = &As[c1 * 512];
  bf16* lB0 = &Bs[c0 * 512]; bf16* lB1 = &Bs[c1 * 512];

  f32x4 acc[4][4] = {};
  int nk = K >> 5;
  for (int kk = 0; kk < nk; ++kk) {
    load_lds16(ap0, lA0);
    load_lds16(ap1, lA1);
    load_lds16(bp0, lB0);
    load_lds16(bp1, lB1);
    ap0 += 32; ap1 += 32; bp0 += 32; bp1 += 32;
    __syncthreads();
    bf16x8 a[4], b[4];
#pragma unroll
    for (int t4 = 0; t4 < 4; ++t4) {
      a[t4] = *(const bf16x8*)(&As[(wr * 64 + t4 * 16 + lr) * 32 + lg * 8]);
      b[t4] = *(const bf16x8*)(&Bs[(wc * 64 + t4 * 16 + lr) * 32 + lg * 8]);
    }
#pragma unroll
    for (int i = 0; i < 4; ++i)
#pragma unroll
      for (int j = 0; j < 4; ++j)
        acc[i][j] = __builtin_amdgcn_mfma_f32_16x16x32_bf16(a[i], b[j], acc[i][j], 0, 0, 0);
    __syncthreads();
  }

  // epilogue
  float bs[4];
#pragma unroll
  for (int j = 0; j < 4; ++j) bs[j] = bias[bcol * 128 + wc * 64 + j * 16 + lr];

#pragma unroll
  for (int i = 0; i < 4; ++i) {
#pragma unroll
    for (int r = 0; r < 4; ++r) {
      int lrow = brow * 128 + wr * 64 + i * 16 + lg * 4 + r;  // chunk-local row
      int grow = row0 + lrow;                                  // global row
      int w_ = 0, n_ = 0; size_t tok = 0;
      if (EPI == 0 || EPI == 1) {
        w_ = grow / 49; n_ = grow - w_ * 49;
        if (EPI == 1) {
          int b_ = w_ >> 6, wi = w_ & 63;
          int wy = wi >> 3, wx = wi & 7;
          int py = n_ / 7, px = n_ - py * 7;
          int rr = wy * 7 + py, cc = wx * 7 + px;
          int ro = rr + 3; if (ro >= 56) ro -= 56;
          int co = cc + 3; if (co >= 56) co -= 56;
          tok = (size_t)b_ * 3136 + ro * 56 + co;
        }
      }
#pragma unroll
      for (int j = 0; j < 4; ++j) {
        int col = bcol * 128 + wc * 64 + j * 16 + lr;
        float val = acc[i][j][r] + bs[j];
        if (EPI == 0) {
          int which = (col >= 768) ? 2 : (col >= 384 ? 1 : 0);
          int cc = col - which * 384;
          int h = cc >> 5, dcl = cc & 31;
          size_t base = (size_t)w_ * WBLK + (size_t)which * NH * HBLK + (size_t)h * HBLK;
          size_t addr = (which == 2) ? base + (size_t)dcl * NPAD + n_ : base + (size_t)n_ * HD + dcl;
          ((bf16*)outp)[addr] = __float2bfloat16(val);
        } else if (EPI == 1) {
          size_t oidx = tok * 384 + col;
          ((float*)outp)[oidx] = val + extra[oidx];
        } else if (EPI == 2) {
          float gv = 0.5f * val * (1.0f + erff(val * 0.70710678118654752f));
          ((bf16*)outp)[(size_t)lrow * 1536 + col] = __float2bfloat16(gv);
        } else {
          size_t oidx = (size_t)grow * 384 + col;
          ((float*)outp)[oidx] = val + extra[oidx];
        }
      }
    }
  }
}

// ---------------- windowed attention: 1 block per window, 4 waves x 3 heads
__global__ __launch_bounds__(256) void attn_kernel(const bf16* __restrict__ qkv,
                                                   const float* __restrict__ rel,
                                                   bf16* __restrict__ attn_out) {
  __shared__ __align__(16) bf16 P[4][64 * 72];
  int wv = threadIdx.x >> 6, lane = threadIdx.x & 63;
  int lr = lane & 15, lg = lane >> 4;
  int w = blockIdx.x;
  int wi = w & 63, wy = wi >> 3, wx = wi & 7;
  const bf16* base = qkv + (size_t)w * WBLK;
  bf16* Pl = &P[wv][0];
  const float scale = 0.17677669529663689f;

  for (int hh = 0; hh < 3; ++hh) {
    int h = wv + hh * 4;
    const bf16* Q  = base + (size_t)h * HBLK;
    const bf16* Kp = base + (size_t)(NH + h) * HBLK;
    const bf16* Vt = base + (size_t)(2 * NH + h) * HBLK;

    bf16x8 qa[4], kb[4];
#pragma unroll
    for (int t = 0; t < 4; ++t) {
      qa[t] = *(const bf16x8*)(Q  + (t * 16 + lr) * 32 + lg * 8);
      kb[t] = *(const bf16x8*)(Kp + (t * 16 + lr) * 32 + lg * 8);
    }
    f32x4 S[4][4] = {};
#pragma unroll
    for (int i = 0; i < 4; ++i)
#pragma unroll
      for (int j = 0; j < 4; ++j)
        S[i][j] = __builtin_amdgcn_mfma_f32_16x16x32_bf16(qa[i], kb[j], S[i][j], 0, 0, 0);

    // bias + mask + softmax, row = i*16 + lg*4 + r (query), col = j*16 + lr (key)
#pragma unroll
    for (int i = 0; i < 4; ++i) {
#pragma unroll
      for (int r = 0; r < 4; ++r) {
        int row = i * 16 + lg * 4 + r;
        bool rowok = row < 49;
        int py = row / 7, px = row - py * 7;
        int regi = 0;
        if (rowok) {
          int ry = wy * 7 + py, rx = wx * 7 + px;
          int ly = ry < 49 ? 0 : (ry < 53 ? 1 : 2);
          int lx = rx < 49 ? 0 : (rx < 53 ? 1 : 2);
          regi = ly * 3 + lx;
        }
        float sv[4]; float m = -1e30f;
#pragma unroll
        for (int j = 0; j < 4; ++j) {
          int col = j * 16 + lr;
          float s = -1e30f;
          if (rowok && col < 49) {
            int qy = col / 7, qx = col - qy * 7;
            int cy = wy * 7 + qy, cx = wx * 7 + qx;
            int lyc = cy < 49 ? 0 : (cy < 53 ? 1 : 2);
            int lxc = cx < 49 ? 0 : (cx < 53 ? 1 : 2);
            int regj = lyc * 3 + lxc;
            int ridx = (py - qy + 6) * 13 + (px - qx + 6);
            s = S[i][j][r] * scale + rel[ridx * 12 + h] + (regi == regj ? 0.f : -100.f);
          }
          sv[j] = s;
          m = fmaxf(m, s);
        }
        m = fmaxf(m, __shfl_xor(m, 1));
        m = fmaxf(m, __shfl_xor(m, 2));
        m = fmaxf(m, __shfl_xor(m, 4));
        m = fmaxf(m, __shfl_xor(m, 8));
        float ev[4]; float sum = 0.f;
#pragma unroll
        for (int j = 0; j < 4; ++j) { ev[j] = __expf(sv[j] - m); sum += ev[j]; }
        sum += __shfl_xor(sum, 1);
        sum += __shfl_xor(sum, 2);
        sum += __shfl_xor(sum, 4);
        sum += __shfl_xor(sum, 8);
        float inv = 1.0f / sum;
#pragma unroll
        for (int j = 0; j < 4; ++j)
          Pl[row * 72 + j * 16 + lr] = __float2bfloat16(ev[j] * inv);
      }
    }

    // PV: O(64x32) = P(64x64) * V(64x32); V from transposed layout Vt (32 x 64)
    bf16x8 vb[2][2];
#pragma unroll
    for (int kt = 0; kt < 2; ++kt)
#pragma unroll
      for (int cj = 0; cj < 2; ++cj)
        vb[kt][cj] = *(const bf16x8*)(Vt + (cj * 16 + lr) * 64 + kt * 32 + lg * 8);
    f32x4 O[4][2] = {};
#pragma unroll
    for (int i = 0; i < 4; ++i) {
#pragma unroll
      for (int kt = 0; kt < 2; ++kt) {
        bf16x8 pa = *(const bf16x8*)(Pl + (i * 16 + lr) * 72 + kt * 32 + lg * 8);
#pragma unroll
        for (int cj = 0; cj < 2; ++cj)
          O[i][cj] = __builtin_amdgcn_mfma_f32_16x16x32_bf16(pa, vb[kt][cj], O[i][cj], 0, 0, 0);
      }
    }
#pragma unroll
    for (int i = 0; i < 4; ++i)
#pragma unroll
      for (int cj = 0; cj < 2; ++cj)
#pragma unroll
        for (int r = 0; r < 4; ++r) {
          int n = i * 16 + lg * 4 + r;
          if (n < 49)
            attn_out[((size_t)w * 49 + n) * 384 + h * 32 + cj * 16 + lr] =
                __float2bfloat16(O[i][cj][r]);
        }
  }
}

extern "C" void kernel_launch(void* const* d_in, const int* in_sizes, int n_in,
                              void* d_out, int out_size, void* d_ws, size_t ws_size,
                              hipStream_t stream) {
  (void)in_sizes; (void)n_in; (void)out_size;
  const float* x     = (const float*)d_in[0];
  const float* g1    = (const float*)d_in[1];
  const float* be1   = (const float*)d_in[2];
  const float* w_qkv = (const float*)d_in[3];
  const float* b_qkv = (const float*)d_in[4];
  const float* rel   = (const float*)d_in[5];
  const float* w_pr  = (const float*)d_in[6];
  const float* b_pr  = (const float*)d_in[7];
  const float* g2    = (const float*)d_in[8];
  const float* be2   = (const float*)d_in[9];
  const float* w1    = (const float*)d_in[10];
  const float* b1    = (const float*)d_in[11];
  const float* w2    = (const float*)d_in[12];
  const float* b2    = (const float*)d_in[13];
  float* out = (float*)d_out;

  if (ws_size < 390070272u) return;  // layout below needs ~372 MiB

  char* ws = (char*)d_ws;
  bf16* wqkvT = (bf16*)(ws);                     // 1152 x 384
  bf16* wprT  = (bf16*)(ws + 884736);            // 384 x 384
  bf16* w1T   = (bf16*)(ws + 1179648);           // 1536 x 384
  bf16* w2T   = (bf16*)(ws + 2359296);           // 384 x 1536
  bf16* xw    = (bf16*)(ws + (4u << 20));        // 100352 x 384 bf16 (also attn_out)
  bf16* qkv   = (bf16*)(ws + (84u << 20));       // 2048 * 73728 bf16 padded QKV
  bf16* m_in  = qkv;                             // reuse after attention
  bf16* h1    = (bf16*)(ws + (164u << 20));      // 50176 x 1536 bf16 chunk

  cast_transpose<<<dim3((442368 + 255) / 256), 256, 0, stream>>>(w_qkv, wqkvT, 384, 1152);
  cast_transpose<<<dim3((147456 + 255) / 256), 256, 0, stream>>>(w_pr, wprT, 384, 384);
  cast_transpose<<<dim3((589824 + 255) / 256), 256, 0, stream>>>(w1, w1T, 384, 1536);
  cast_transpose<<<dim3((589824 + 255) / 256), 256, 0, stream>>>(w2, w2T, 1536, 384);

  zero_pads<<<dim3((NWIN * 3 * NH * 15 * HD + 255) / 256), 256, 0, stream>>>(qkv);

  ln_kernel<0><<<dim3(NTOK / 4), 256, 0, stream>>>(x, g1, be1, xw);

  // QKV: 9 bcols x 784 brows = 7056 blocks (7056/8=882, 882/9=98 -> swizzle exact)
  gemm_bf16<0><<<dim3(7056), 256, 0, stream>>>(xw, wqkvT, 384, 9, 0, b_qkv, nullptr, (void*)qkv);

  attn_kernel<<<dim3(NWIN), 256, 0, stream>>>(qkv, rel, xw);

  // proj: 3 x 784 = 2352 (2352/8=294, /3=98)
  gemm_bf16<1><<<dim3(2352), 256, 0, stream>>>(xw, wprT, 384, 3, 0, b_pr, x, (void*)out);

  ln_kernel<1><<<dim3(NTOK / 4), 256, 0, stream>>>(out, g2, be2, m_in);

  for (int c = 0; c < 2; ++c) {
    // MLP1: 12 x 392 = 4704 (4704/8=588, /12=49)
    gemm_bf16<2><<<dim3(4704), 256, 0, stream>>>(m_in + (size_t)c * 50176 * 384, w1T, 384,
                                                 12, c * 50176, b1, nullptr, (void*)h1);
    // MLP2: 3 x 392 = 1176 (1176/8=147, /3=49)
    gemm_bf16<3><<<dim3(1176), 256, 0, stream>>>(h1, w2T, 1536, 3, c * 50176, b2, out,
                                                 (void*)out);
  }
}

// Round 3
// 1156.799 us; speedup vs baseline: 1.0575x; 1.0286x over previous
//
#include <hip/hip_runtime.h>
#include <hip/hip_bf16.h>
#include <math.h>

typedef __attribute__((ext_vector_type(8))) short bf16x8;
typedef __attribute__((ext_vector_type(4))) short bf16x4;
typedef __attribute__((ext_vector_type(4))) float f32x4;
typedef __hip_bfloat16 bf16;

#define NH 12
#define HD 32
#define NPAD 64
#define NWIN 2048
#define NTOK 100352
#define HBLK (NPAD*HD)        // 2048 elements per (head) block
#define WBLK (3*NH*HBLK)      // 73728 elements per window

__device__ inline float wave_sum(float v) {
#pragma unroll
  for (int off = 32; off; off >>= 1) v += __shfl_xor(v, off);
  return v;
}

__device__ inline void load_lds16(const bf16* g, bf16* l) {
  __builtin_amdgcn_global_load_lds((const __attribute__((address_space(1))) void*)g,
                                   (__attribute__((address_space(3))) void*)l, 16, 0, 0);
}

__device__ inline short bfbits(float f) {
  bf16 h = __float2bfloat16(f);
  return *(short*)&h;
}

// ---------------- weight cast + transpose: in (K x N) f32 -> out (N x K) bf16
__global__ __launch_bounds__(256) void cast_transpose(const float* __restrict__ in,
                                                      bf16* __restrict__ out, int K, int N) {
  int e = blockIdx.x * 256 + threadIdx.x;
  if (e >= K * N) return;
  int n = e / K, k = e - n * K;
  out[e] = __float2bfloat16(in[k * N + n]);
}

// ---------------- zero the 15 pad rows of every (w, which, h) QKV block
__global__ __launch_bounds__(256) void zero_pads(bf16* __restrict__ qkv) {
  int idx = blockIdx.x * 256 + threadIdx.x;
  const int total = NWIN * 3 * NH * 15 * HD;
  if (idx >= total) return;
  int d = idx & 31; int rest = idx >> 5;
  int n = 49 + (rest % 15); rest /= 15;
  int h = rest % NH; rest /= NH;
  int which = rest % 3; int w = rest / 3;
  size_t base = (size_t)w * WBLK + (size_t)which * NH * HBLK + (size_t)h * HBLK;
  size_t addr = (which == 2) ? base + (size_t)d * NPAD + n : base + (size_t)n * HD + d;
  qkv[addr] = __float2bfloat16(0.0f);
}

// ---------------- LayerNorm. MODE 0: LN1 + roll(-3,-3) + window partition (src mapped)
//                  MODE 1: LN2 straight rows
template <int MODE>
__global__ __launch_bounds__(256) void ln_kernel(const float* __restrict__ x,
                                                 const float* __restrict__ g,
                                                 const float* __restrict__ be,
                                                 bf16* __restrict__ out) {
  int wv = threadIdx.x >> 6, lane = threadIdx.x & 63;
  int t = blockIdx.x * 4 + wv;
  size_t src;
  if (MODE == 0) {
    int w = t / 49, n = t - w * 49;
    int b = w >> 6, wi = w & 63;
    int wy = wi >> 3, wx = wi & 7;
    int py = n / 7, px = n - py * 7;
    int rr = wy * 7 + py, cc = wx * 7 + px;
    int ro = rr + 3; if (ro >= 56) ro -= 56;
    int co = cc + 3; if (co >= 56) co -= 56;
    src = (size_t)b * 3136 + ro * 56 + co;
  } else {
    src = (size_t)t;
  }
  const float2* row2 = (const float2*)(x + src * 384);
  float2 v[3]; float s = 0.f;
#pragma unroll
  for (int j = 0; j < 3; ++j) { v[j] = row2[lane + 64 * j]; s += v[j].x + v[j].y; }
  s = wave_sum(s);
  float mu = s * (1.f / 384.f);
  float q = 0.f;
#pragma unroll
  for (int j = 0; j < 3; ++j) {
    float dx = v[j].x - mu, dy = v[j].y - mu;
    q += dx * dx + dy * dy;
  }
  q = wave_sum(q);
  float rs = rsqrtf(q * (1.f / 384.f) + 1e-5f);
  uint* o = (uint*)(out + (size_t)t * 384);
  const float2* g2 = (const float2*)g;
  const float2* b2 = (const float2*)be;
#pragma unroll
  for (int j = 0; j < 3; ++j) {
    int c2 = lane + 64 * j;
    float2 gg = g2[c2], bb = b2[c2];
    float ox = (v[j].x - mu) * rs * gg.x + bb.x;
    float oy = (v[j].y - mu) * rs * gg.y + bb.y;
    o[c2] = (uint)(unsigned short)bfbits(ox) | ((uint)(unsigned short)bfbits(oy) << 16);
  }
}

// ---------------- GEMM: C = A(M x K) * B^T, 128x128 tile, BK=64, swapped-operand MFMA
// (thread holds 4 consecutive C-cols), global_load_lds w/ pre-swizzled source, XOR-swizzled
// ds_read. XCD-swizzled 1-D grid. EPI: 0=QKV scatter, 1=proj+residual+reverse,
// 2=GELU->h1, 3=out=acc+b2+x1 -> d_out
template <int EPI>
__global__ __launch_bounds__(256) void gemm_bf16(const bf16* __restrict__ A,
                                                 const bf16* __restrict__ BT,
                                                 int K, int NCOL, int row0,
                                                 const float* __restrict__ bias,
                                                 const float* __restrict__ extra,
                                                 void* __restrict__ outp) {
  __shared__ __align__(16) bf16 As[128 * 64];
  __shared__ __align__(16) bf16 Bs[128 * 64];
  int tid = threadIdx.x;
  int lane = tid & 63, wv = tid >> 6;
  int wr = wv >> 1, wc = wv & 1;
  int lr = lane & 15, lg = lane >> 4;

  // XCD-aware swizzle: nwg % 8 == 0 and (nwg/8) % NCOL == 0 guaranteed by launch.
  int nwg = gridDim.x;
  int dd = blockIdx.x;
  int xcd = dd & 7, idx = dd >> 3;
  int perx = nwg >> 3;
  int qq = idx / NCOL;
  int brow = xcd * (perx / NCOL) + qq;
  int bcol = idx - qq * NCOL;

  const bf16* Ab = A + (size_t)brow * 128 * K;
  const bf16* Bb = BT + (size_t)bcol * 128 * K;

  // staging: wave wv stages chunks wv*4+c (c=0..3) of each buffer; chunk = 8 rows of 64.
  // LDS[row][c] holds global elem (row, c ^ ((row&7)<<3)); dest linear (rule #21).
  int srow = lane >> 3;                               // row&7 within chunk
  int scol = ((lane & 7) * 8) ^ (srow << 3);          // pre-swizzled source col
  const bf16* apB = Ab + (size_t)(wv * 32 + srow) * K + scol;
  const bf16* bpB = Bb + (size_t)(wv * 32 + srow) * K + scol;
  bf16* lA = &As[wv * 2048];
  bf16* lB = &Bs[wv * 2048];

  f32x4 acc[4][4] = {};
  int nk = K >> 6;
  for (int kk = 0; kk < nk; ++kk) {
#pragma unroll
    for (int c = 0; c < 4; ++c) {
      load_lds16(apB + (size_t)c * 8 * K, lA + c * 512);
      load_lds16(bpB + (size_t)c * 8 * K, lB + c * 512);
    }
    apB += 64; bpB += 64;
    __syncthreads();
#pragma unroll
    for (int h = 0; h < 2; ++h) {
      bf16x8 a[4], b[4];
      int koff = (h * 32 + lg * 8) ^ ((lr & 7) << 3);
#pragma unroll
      for (int t4 = 0; t4 < 4; ++t4) {
        a[t4] = *(const bf16x8*)(&As[(wr * 64 + t4 * 16 + lr) * 64 + koff]);
        b[t4] = *(const bf16x8*)(&Bs[(wc * 64 + t4 * 16 + lr) * 64 + koff]);
      }
#pragma unroll
      for (int i = 0; i < 4; ++i)
#pragma unroll
        for (int j = 0; j < 4; ++j)
          acc[i][j] = __builtin_amdgcn_mfma_f32_16x16x32_bf16(b[j], a[i], acc[i][j], 0, 0, 0);
    }
    __syncthreads();
  }

  // epilogue: swapped layout -> C row = i*16+lr, C cols = j*16 + lg*4 + (0..3)
  float4 bias4[4];
#pragma unroll
  for (int j = 0; j < 4; ++j)
    bias4[j] = *(const float4*)(bias + bcol * 128 + wc * 64 + j * 16 + lg * 4);

#pragma unroll
  for (int i = 0; i < 4; ++i) {
    int lrow = brow * 128 + wr * 64 + i * 16 + lr;
    int grow = row0 + lrow;
    int w_ = 0, n_ = 0; size_t tok = 0;
    if (EPI == 0 || EPI == 1) {
      w_ = grow / 49; n_ = grow - w_ * 49;
      if (EPI == 1) {
        int b_ = w_ >> 6, wi = w_ & 63;
        int wy = wi >> 3, wx = wi & 7;
        int py = n_ / 7, px = n_ - py * 7;
        int rr = wy * 7 + py, cc2 = wx * 7 + px;
        int ro = rr + 3; if (ro >= 56) ro -= 56;
        int co = cc2 + 3; if (co >= 56) co -= 56;
        tok = (size_t)b_ * 3136 + ro * 56 + co;
      }
    }
#pragma unroll
    for (int j = 0; j < 4; ++j) {
      int col = bcol * 128 + wc * 64 + j * 16 + lg * 4;
      float v0 = acc[i][j][0] + bias4[j].x;
      float v1 = acc[i][j][1] + bias4[j].y;
      float v2 = acc[i][j][2] + bias4[j].z;
      float v3 = acc[i][j][3] + bias4[j].w;
      if (EPI == 0) {
        int which = (col >= 768) ? 2 : (col >= 384 ? 1 : 0);
        int cc = col - which * 384;
        int hh = cc >> 5, d0 = cc & 31;
        size_t base = (size_t)w_ * WBLK + (size_t)which * NH * HBLK + (size_t)hh * HBLK;
        if (which == 2) {
          bf16* vp = (bf16*)outp + base + (size_t)d0 * NPAD + n_;
          vp[0] = __float2bfloat16(v0);
          vp[NPAD] = __float2bfloat16(v1);
          vp[2 * NPAD] = __float2bfloat16(v2);
          vp[3 * NPAD] = __float2bfloat16(v3);
        } else {
          bf16x4 p = {bfbits(v0), bfbits(v1), bfbits(v2), bfbits(v3)};
          *(bf16x4*)((bf16*)outp + base + (size_t)n_ * HD + d0) = p;
        }
      } else if (EPI == 1) {
        size_t oidx = tok * 384 + col;
        float4 e = *(const float4*)(extra + oidx);
        float4 o = {v0 + e.x, v1 + e.y, v2 + e.z, v3 + e.w};
        *(float4*)((float*)outp + oidx) = o;
      } else if (EPI == 2) {
        float g0 = 0.5f * v0 * (1.0f + erff(v0 * 0.70710678118654752f));
        float g1 = 0.5f * v1 * (1.0f + erff(v1 * 0.70710678118654752f));
        float g2 = 0.5f * v2 * (1.0f + erff(v2 * 0.70710678118654752f));
        float g3 = 0.5f * v3 * (1.0f + erff(v3 * 0.70710678118654752f));
        bf16x4 p = {bfbits(g0), bfbits(g1), bfbits(g2), bfbits(g3)};
        *(bf16x4*)((bf16*)outp + (size_t)lrow * 1536 + col) = p;
      } else {
        size_t oidx = (size_t)grow * 384 + col;
        float4 e = *(const float4*)(extra + oidx);
        float4 o = {v0 + e.x, v1 + e.y, v2 + e.z, v3 + e.w};
        *(float4*)((float*)outp + oidx) = o;
      }
    }
  }
}

// ---------------- windowed attention: 1 block per window, 4 waves x 3 heads
__global__ __launch_bounds__(256) void attn_kernel(const bf16* __restrict__ qkv,
                                                   const float* __restrict__ rel,
                                                   bf16* __restrict__ attn_out) {
  __shared__ __align__(16) bf16 P[4][64 * 72];
  int wv = threadIdx.x >> 6, lane = threadIdx.x & 63;
  int lr = lane & 15, lg = lane >> 4;
  int w = blockIdx.x;
  int wi = w & 63, wy = wi >> 3, wx = wi & 7;
  const bf16* base = qkv + (size_t)w * WBLK;
  bf16* Pl = &P[wv][0];
  const float scale = 0.17677669529663689f;

  for (int hh = 0; hh < 3; ++hh) {
    int h = wv + hh * 4;
    const bf16* Q  = base + (size_t)h * HBLK;
    const bf16* Kp = base + (size_t)(NH + h) * HBLK;
    const bf16* Vt = base + (size_t)(2 * NH + h) * HBLK;

    bf16x8 qa[4], kb[4];
#pragma unroll
    for (int t = 0; t < 4; ++t) {
      qa[t] = *(const bf16x8*)(Q  + (t * 16 + lr) * 32 + lg * 8);
      kb[t] = *(const bf16x8*)(Kp + (t * 16 + lr) * 32 + lg * 8);
    }
    f32x4 S[4][4] = {};
#pragma unroll
    for (int i = 0; i < 4; ++i)
#pragma unroll
      for (int j = 0; j < 4; ++j)
        S[i][j] = __builtin_amdgcn_mfma_f32_16x16x32_bf16(qa[i], kb[j], S[i][j], 0, 0, 0);

    // bias + mask + softmax, row = i*16 + lg*4 + r (query), col = j*16 + lr (key)
#pragma unroll
    for (int i = 0; i < 4; ++i) {
#pragma unroll
      for (int r = 0; r < 4; ++r) {
        int row = i * 16 + lg * 4 + r;
        bool rowok = row < 49;
        int py = row / 7, px = row - py * 7;
        int regi = 0;
        if (rowok) {
          int ry = wy * 7 + py, rx = wx * 7 + px;
          int ly = ry < 49 ? 0 : (ry < 53 ? 1 : 2);
          int lx = rx < 49 ? 0 : (rx < 53 ? 1 : 2);
          regi = ly * 3 + lx;
        }
        float sv[4]; float m = -1e30f;
#pragma unroll
        for (int j = 0; j < 4; ++j) {
          int col = j * 16 + lr;
          float s = -1e30f;
          if (rowok && col < 49) {
            int qy = col / 7, qx = col - qy * 7;
            int cy = wy * 7 + qy, cx = wx * 7 + qx;
            int lyc = cy < 49 ? 0 : (cy < 53 ? 1 : 2);
            int lxc = cx < 49 ? 0 : (cx < 53 ? 1 : 2);
            int regj = lyc * 3 + lxc;
            int ridx = (py - qy + 6) * 13 + (px - qx + 6);
            s = S[i][j][r] * scale + rel[ridx * 12 + h] + (regi == regj ? 0.f : -100.f);
          }
          sv[j] = s;
          m = fmaxf(m, s);
        }
        m = fmaxf(m, __shfl_xor(m, 1));
        m = fmaxf(m, __shfl_xor(m, 2));
        m = fmaxf(m, __shfl_xor(m, 4));
        m = fmaxf(m, __shfl_xor(m, 8));
        float ev[4]; float sum = 0.f;
#pragma unroll
        for (int j = 0; j < 4; ++j) { ev[j] = __expf(sv[j] - m); sum += ev[j]; }
        sum += __shfl_xor(sum, 1);
        sum += __shfl_xor(sum, 2);
        sum += __shfl_xor(sum, 4);
        sum += __shfl_xor(sum, 8);
        float inv = 1.0f / sum;
#pragma unroll
        for (int j = 0; j < 4; ++j)
          Pl[row * 72 + j * 16 + lr] = __float2bfloat16(ev[j] * inv);
      }
    }

    // PV: O(64x32) = P(64x64) * V(64x32); V from transposed layout Vt (32 x 64)
    bf16x8 vb[2][2];
#pragma unroll
    for (int kt = 0; kt < 2; ++kt)
#pragma unroll
      for (int cj = 0; cj < 2; ++cj)
        vb[kt][cj] = *(const bf16x8*)(Vt + (cj * 16 + lr) * 64 + kt * 32 + lg * 8);
    f32x4 O[4][2] = {};
#pragma unroll
    for (int i = 0; i < 4; ++i) {
#pragma unroll
      for (int kt = 0; kt < 2; ++kt) {
        bf16x8 pa = *(const bf16x8*)(Pl + (i * 16 + lr) * 72 + kt * 32 + lg * 8);
#pragma unroll
        for (int cj = 0; cj < 2; ++cj)
          O[i][cj] = __builtin_amdgcn_mfma_f32_16x16x32_bf16(pa, vb[kt][cj], O[i][cj], 0, 0, 0);
      }
    }
#pragma unroll
    for (int i = 0; i < 4; ++i)
#pragma unroll
      for (int cj = 0; cj < 2; ++cj)
#pragma unroll
        for (int r = 0; r < 4; ++r) {
          int n = i * 16 + lg * 4 + r;
          if (n < 49)
            attn_out[((size_t)w * 49 + n) * 384 + h * 32 + cj * 16 + lr] =
                __float2bfloat16(O[i][cj][r]);
        }
  }
}

extern "C" void kernel_launch(void* const* d_in, const int* in_sizes, int n_in,
                              void* d_out, int out_size, void* d_ws, size_t ws_size,
                              hipStream_t stream) {
  (void)in_sizes; (void)n_in; (void)out_size;
  const float* x     = (const float*)d_in[0];
  const float* g1    = (const float*)d_in[1];
  const float* be1   = (const float*)d_in[2];
  const float* w_qkv = (const float*)d_in[3];
  const float* b_qkv = (const float*)d_in[4];
  const float* rel   = (const float*)d_in[5];
  const float* w_pr  = (const float*)d_in[6];
  const float* b_pr  = (const float*)d_in[7];
  const float* g2    = (const float*)d_in[8];
  const float* be2   = (const float*)d_in[9];
  const float* w1    = (const float*)d_in[10];
  const float* b1    = (const float*)d_in[11];
  const float* w2    = (const float*)d_in[12];
  const float* b2    = (const float*)d_in[13];
  float* out = (float*)d_out;

  if (ws_size < 390070272u) return;  // layout below needs ~372 MiB

  char* ws = (char*)d_ws;
  bf16* wqkvT = (bf16*)(ws);                     // 1152 x 384
  bf16* wprT  = (bf16*)(ws + 884736);            // 384 x 384
  bf16* w1T   = (bf16*)(ws + 1179648);           // 1536 x 384
  bf16* w2T   = (bf16*)(ws + 2359296);           // 384 x 1536
  bf16* xw    = (bf16*)(ws + (4u << 20));        // 100352 x 384 bf16 (also attn_out)
  bf16* qkv   = (bf16*)(ws + (84u << 20));       // 2048 * 73728 bf16 padded QKV
  bf16* m_in  = qkv;                             // reuse after attention
  bf16* h1    = (bf16*)(ws + (164u << 20));      // 50176 x 1536 bf16 chunk

  cast_transpose<<<dim3((442368 + 255) / 256), 256, 0, stream>>>(w_qkv, wqkvT, 384, 1152);
  cast_transpose<<<dim3((147456 + 255) / 256), 256, 0, stream>>>(w_pr, wprT, 384, 384);
  cast_transpose<<<dim3((589824 + 255) / 256), 256, 0, stream>>>(w1, w1T, 384, 1536);
  cast_transpose<<<dim3((589824 + 255) / 256), 256, 0, stream>>>(w2, w2T, 1536, 384);

  zero_pads<<<dim3((NWIN * 3 * NH * 15 * HD + 255) / 256), 256, 0, stream>>>(qkv);

  ln_kernel<0><<<dim3(NTOK / 4), 256, 0, stream>>>(x, g1, be1, xw);

  // QKV: 9 bcols x 784 brows = 7056 blocks (7056/8=882, 882/9=98 -> swizzle exact)
  gemm_bf16<0><<<dim3(7056), 256, 0, stream>>>(xw, wqkvT, 384, 9, 0, b_qkv, nullptr, (void*)qkv);

  attn_kernel<<<dim3(NWIN), 256, 0, stream>>>(qkv, rel, xw);

  // proj: 3 x 784 = 2352 (2352/8=294, /3=98)
  gemm_bf16<1><<<dim3(2352), 256, 0, stream>>>(xw, wprT, 384, 3, 0, b_pr, x, (void*)out);

  ln_kernel<1><<<dim3(NTOK / 4), 256, 0, stream>>>(out, g2, be2, m_in);

  for (int c = 0; c < 2; ++c) {
    // MLP1: 12 x 392 = 4704 (4704/8=588, /12=49)
    gemm_bf16<2><<<dim3(4704), 256, 0, stream>>>(m_in + (size_t)c * 50176 * 384, w1T, 384,
                                                 12, c * 50176, b1, nullptr, (void*)h1);
    // MLP2: 3 x 392 = 1176 (1176/8=147, /3=49)
    gemm_bf16<3><<<dim3(1176), 256, 0, stream>>>(h1, w2T, 1536, 3, c * 50176, b2, out,
                                                 (void*)out);
  }
}